// Round 8
// baseline (418.255 us; speedup 1.0000x reference)
//
#include <hip/hip_runtime.h>
#include <hip/hip_cooperative_groups.h>
#include <math.h>

namespace cg = cooperative_groups;

#define BB 8
#define HH 256
#define KK 256
#define EE 128
#define NBIN 1024            // 1000 value-vocab bins padded to 1024
#define GRID 1024            // 2 (b,h) pairs per block; 4 blocks/CU co-resident
#define BPB 128              // phase-A blocks per b
#define CHUNK 16             // bins per phase-B block
#define NCH (NBIN / CHUNK)   // 64 chunks per b

// DPP-based add: x + dpp_mov(x).
template <int CTRL, int RM>
__device__ __forceinline__ float dpp_add(float x) {
    int d = __builtin_amdgcn_update_dpp(0, __float_as_int(x), CTRL, RM, 0xf, true);
    return x + __int_as_float(d);
}
// Sum within each 32-lane half; lanes 31/63 hold the result.
__device__ __forceinline__ float dpp_reduce_half(float x) {
    x = dpp_add<0x111, 0xf>(x);  // row_shr:1
    x = dpp_add<0x112, 0xf>(x);  // row_shr:2
    x = dpp_add<0x114, 0xf>(x);  // row_shr:4
    x = dpp_add<0x118, 0xf>(x);  // row_shr:8
    x = dpp_add<0x142, 0xa>(x);  // row_bcast:15 -> lanes 31,63 have 32-sums
    return x;
}
// Sum over all 64 lanes; lane 63 holds the result.
__device__ __forceinline__ float dpp_reduce_wave(float x) {
    x = dpp_reduce_half(x);
    x = dpp_add<0x143, 0xc>(x);  // row_bcast:31 -> lane 63 has 64-sum
    return x;
}

__global__ __launch_bounds__(256, 4) void kvmn_coop(
    const float* __restrict__ hidden,     // [B,H,E]
    const float* __restrict__ key_emb,    // [VOCAB,E]
    const float* __restrict__ value_emb,  // [FVOCAB,E]
    const int*   __restrict__ key_seq,    // [B,K]
    const int*   __restrict__ value_seq,  // [B,H,K]
    const int*   __restrict__ mask,       // [B,H,K]
    float* __restrict__ part_hist,        // [GRID, NBIN]     (4 MB ws)
    float* __restrict__ partial_out,      // [B, NCH, EE]     (256 KB ws)
    int*   __restrict__ c_part,           // [GRID]           (4 KB ws)
    float* __restrict__ out)              // [B, E]
{
    __shared__ float sh_u[2][KK];
    __shared__ float hist[NBIN];
    __shared__ float fslot[2][4];
    __shared__ int   islot[2][4];
    __shared__ float red[CHUNK][17];
    __shared__ float Hc[CHUNK];
    __shared__ float gs[2][EE];
    __shared__ int   sh_c[256];
    __shared__ float sh_cf;

    cg::grid_group grid = cg::this_grid();

    const int bid  = blockIdx.x;
    const int tid  = threadIdx.x;        // == k in phase A
    const int w    = tid >> 6;
    const int lane = tid & 63;
    const int half = lane >> 5;
    const int sub  = lane & 31;

    // ================= Phase A: attention -> per-block histogram =================
    {
        const int b  = bid >> 7;          // 2 (b,h) pairs per block, same b
        const int h0 = (bid * 2) & 255;

        const int ksreg = key_seq[b * KK + tid];

        float4 h4[2];
        #pragma unroll
        for (int j = 0; j < 2; ++j)
            h4[j] = *(const float4*)&hidden[((size_t)b * HH + h0 + j) * EE + sub * 4];

        *(float4*)&hist[tid * 4] = make_float4(0.f, 0.f, 0.f, 0.f);

        const float inv_scale = 0.08838834764831845f; // 1/sqrt(128)

        // phase 1: each key row loaded once, dotted with both h rows
        #pragma unroll 8
        for (int i = 0; i < 32; ++i) {
            const int    row = __shfl(ksreg, half * 32 + i, 64);
            const float4 kv  = *(const float4*)&key_emb[(size_t)row * EE + sub * 4];
            const int    k2  = w * 64 + half * 32 + i;
            float p0 = kv.x * h4[0].x + kv.y * h4[0].y + kv.z * h4[0].z + kv.w * h4[0].w;
            float p1 = kv.x * h4[1].x + kv.y * h4[1].y + kv.z * h4[1].z + kv.w * h4[1].w;
            p0 = dpp_reduce_half(p0);
            p1 = dpp_reduce_half(p1);
            if (sub == 31) {
                sh_u[0][k2] = p0 * inv_scale;
                sh_u[1][k2] = p1 * inv_scale;
            }
        }
        __syncthreads();

        // phase 2: d = exp(u)*mask; block denoms; validity flags
        float d[2];
        int   vs[2];
        #pragma unroll
        for (int j = 0; j < 2; ++j) {
            const size_t idx = ((size_t)b * HH + h0 + j) * KK + tid;
            const int m = mask[idx];
            vs[j] = value_seq[idx];
            d[j]  = expf(sh_u[j][tid]) * (float)m;
            const float s = dpp_reduce_wave(d[j]);
            if (lane == 63) fslot[j][w] = s;
            const unsigned long long bal = __ballot(m != 0 && vs[j] != 0);
            if (lane == 0) islot[j][w] = (bal != 0ull) ? 1 : 0;
        }
        __syncthreads();

        // p scatter into the block-shared histogram (sums over both h rows)
        #pragma unroll
        for (int j = 0; j < 2; ++j) {
            const float denom = fslot[j][0] + fslot[j][1] + fslot[j][2] + fslot[j][3];
            const float p = d[j] * (1.0f / (denom + 1e-10f));
            atomicAdd(&hist[vs[j]], p);
        }
        if (tid == 0) {
            const int f0 = islot[0][0] | islot[0][1] | islot[0][2] | islot[0][3];
            const int f1 = islot[1][0] | islot[1][1] | islot[1][2] | islot[1][3];
            c_part[bid] = f0 + f1;        // # of valid h rows in this block
        }
        __syncthreads();

        *(float4*)&part_hist[(size_t)bid * NBIN + tid * 4] = *(float4*)&hist[tid * 4];
    }

    __threadfence();
    grid.sync();

    // ========== Phase B: reduce hists over h + chunk GEMM (512 active blocks) ==========
    if (bid < BB * NCH) {
        const int b    = bid >> 6;        // / NCH
        const int j    = bid & (NCH - 1);
        const int bin0 = j * CHUNK;

        const int bin = tid & 15;
        const int rg  = tid >> 4;         // 16 row-groups of 8 rows
        float s = 0.0f;
        const float* basep = part_hist + (size_t)(b * BPB + rg * 8) * NBIN + bin0 + bin;
        #pragma unroll
        for (int r = 0; r < 8; ++r)
            s += basep[(size_t)r * NBIN];
        red[bin][rg] = s;
        __syncthreads();
        if (tid < CHUNK) {
            float t2 = 0.0f;
            #pragma unroll
            for (int g = 0; g < 16; ++g) t2 += red[tid][g];
            Hc[tid] = t2;
        }
        __syncthreads();

        // chunk GEMM: pout[e] = sum_{i in chunk} Hc[i] * V[bin0+i, e]
        const int e  = tid & 127;
        const int hf = tid >> 7;
        float acc = 0.0f;
        #pragma unroll
        for (int i = 0; i < 8; ++i) {
            const int gb = bin0 + hf * 8 + i;
            if (gb < 1000)
                acc += Hc[hf * 8 + i] * value_emb[(size_t)gb * EE + e];
        }
        gs[hf][e] = acc;
        __syncthreads();
        if (tid < EE)
            partial_out[((size_t)b * NCH + j) * EE + tid] = gs[0][tid] + gs[1][tid];
    }

    __threadfence();
    grid.sync();

    // ========== Phase C: final reduce over chunks + divide (8 active blocks) ==========
    if (bid < BB) {
        const int b  = bid;
        const int e  = tid & 127;
        const int hf = tid >> 7;

        float acc = 0.0f;
        #pragma unroll 8
        for (int q = 0; q < 32; ++q)
            acc += partial_out[((size_t)b * NCH + hf * 32 + q) * EE + e];
        gs[hf][e] = acc;
        sh_c[tid] = (tid < BPB) ? c_part[b * BPB + tid] : 0;
        __syncthreads();
        if (tid == 0) {
            int c = 0;
            for (int i = 0; i < BPB; ++i) c += sh_c[i];
            sh_cf = (float)c;
        }
        __syncthreads();
        if (tid < EE)
            out[b * EE + tid] = (gs[0][tid] + gs[1][tid]) / sh_cf;
    }
}

extern "C" void kernel_launch(void* const* d_in, const int* in_sizes, int n_in,
                              void* d_out, int out_size, void* d_ws, size_t ws_size,
                              hipStream_t stream) {
    const float* hidden    = (const float*)d_in[0];
    const float* key_emb   = (const float*)d_in[1];
    const float* value_emb = (const float*)d_in[2];
    const int*   key_seq   = (const int*)d_in[3];
    const int*   value_seq = (const int*)d_in[4];
    const int*   mask      = (const int*)d_in[5];

    char* ws = (char*)d_ws;
    float* part_hist   = (float*)ws;                               // 4 MB
    float* partial_out = (float*)(ws + (4u << 20));                // 256 KB
    int*   c_part      = (int*)  (ws + (4u << 20) + (256u << 10)); // 4 KB
    float* outp        = (float*)d_out;

    void* args[] = {
        (void*)&hidden, (void*)&key_emb, (void*)&value_emb,
        (void*)&key_seq, (void*)&value_seq, (void*)&mask,
        (void*)&part_hist, (void*)&partial_out, (void*)&c_part, (void*)&outp
    };
    hipLaunchCooperativeKernel((const void*)kvmn_coop, dim3(GRID), dim3(256),
                               args, 0, stream);
    (void)in_sizes; (void)n_in; (void)out_size; (void)ws_size;
}

// Round 9
// 112.492 us; speedup vs baseline: 3.7181x; 3.7181x over previous
//
#include <hip/hip_runtime.h>
#include <math.h>

#define BB 8
#define HH 256
#define KK 256
#define EE 128
#define NBIN 1024            // 1000 value-vocab bins padded to 1024
#define NB1 1024             // K1 blocks: 2 (b,h) pairs each
#define BPB 128              // K1 blocks per b
#define NCH 8                // 128-bin chunks per b in K2

// DPP-based add: x + dpp_mov(x).
template <int CTRL, int RM>
__device__ __forceinline__ float dpp_add(float x) {
    int d = __builtin_amdgcn_update_dpp(0, __float_as_int(x), CTRL, RM, 0xf, true);
    return x + __int_as_float(d);
}
// Sum within each 32-lane half; lanes 31/63 hold the result.
__device__ __forceinline__ float dpp_reduce_half(float x) {
    x = dpp_add<0x111, 0xf>(x);  // row_shr:1
    x = dpp_add<0x112, 0xf>(x);  // row_shr:2
    x = dpp_add<0x114, 0xf>(x);  // row_shr:4
    x = dpp_add<0x118, 0xf>(x);  // row_shr:8
    x = dpp_add<0x142, 0xa>(x);  // row_bcast:15 -> lanes 31,63 have 32-sums
    return x;
}
// Sum over all 64 lanes; lane 63 holds the result.
__device__ __forceinline__ float dpp_reduce_wave(float x) {
    x = dpp_reduce_half(x);
    x = dpp_add<0x143, 0xc>(x);  // row_bcast:31 -> lane 63 has 64-sum
    return x;
}

// ---------------- K1: 1024 blocks, 2 (b,h) pairs each. Attention -> LDS hist. ----------------
__global__ __launch_bounds__(256, 4) void kvmn_attn(
    const float* __restrict__ hidden,     // [B,H,E]
    const float* __restrict__ key_emb,    // [VOCAB,E]
    const int*   __restrict__ key_seq,    // [B,K]
    const int*   __restrict__ value_seq,  // [B,H,K]
    const int*   __restrict__ mask,       // [B,H,K]
    float* __restrict__ part_hist,        // [NB1, NBIN]  (4 MB)
    int*   __restrict__ c_part)           // [NB1]
{
    __shared__ float sh_u[2][KK];
    __shared__ float hist[NBIN];
    __shared__ float fslot[2][4];
    __shared__ int   islot[2][4];

    const int bid  = blockIdx.x;
    const int b    = bid >> 7;           // 128 blocks per b
    const int h0   = (bid & 127) * 2;
    const int tid  = threadIdx.x;        // == k
    const int w    = tid >> 6;
    const int lane = tid & 63;
    const int half = lane >> 5;
    const int sub  = lane & 31;

    const int ksreg = key_seq[b * KK + tid];

    float4 h4[2];
    #pragma unroll
    for (int j = 0; j < 2; ++j)
        h4[j] = *(const float4*)&hidden[((size_t)b * HH + h0 + j) * EE + sub * 4];

    *(float4*)&hist[tid * 4] = make_float4(0.f, 0.f, 0.f, 0.f);

    const float inv_scale = 0.08838834764831845f; // 1/sqrt(128)

    // phase 1: each key row loaded once, dotted with both h rows (register shfl idx)
    #pragma unroll 8
    for (int i = 0; i < 32; ++i) {
        const int    row = __shfl(ksreg, half * 32 + i, 64);
        const float4 kv  = *(const float4*)&key_emb[(size_t)row * EE + sub * 4];
        const int    k2  = w * 64 + half * 32 + i;
        float p0 = kv.x * h4[0].x + kv.y * h4[0].y + kv.z * h4[0].z + kv.w * h4[0].w;
        float p1 = kv.x * h4[1].x + kv.y * h4[1].y + kv.z * h4[1].z + kv.w * h4[1].w;
        p0 = dpp_reduce_half(p0);
        p1 = dpp_reduce_half(p1);
        if (sub == 31) {
            sh_u[0][k2] = p0 * inv_scale;
            sh_u[1][k2] = p1 * inv_scale;
        }
    }
    __syncthreads();

    // phase 2: d = exp(u)*mask; block denoms; validity flags
    float d[2];
    int   vs[2];
    #pragma unroll
    for (int j = 0; j < 2; ++j) {
        const size_t idx = ((size_t)b * HH + h0 + j) * KK + tid;
        const int m = mask[idx];
        vs[j] = value_seq[idx];
        d[j]  = expf(sh_u[j][tid]) * (float)m;
        const float s = dpp_reduce_wave(d[j]);
        if (lane == 63) fslot[j][w] = s;
        const unsigned long long bal = __ballot(m != 0 && vs[j] != 0);
        if (lane == 0) islot[j][w] = (bal != 0ull) ? 1 : 0;
    }
    __syncthreads();

    // p scatter into block-shared histogram (both h rows accumulate together)
    #pragma unroll
    for (int j = 0; j < 2; ++j) {
        const float denom = fslot[j][0] + fslot[j][1] + fslot[j][2] + fslot[j][3];
        const float p = d[j] * (1.0f / (denom + 1e-10f));
        atomicAdd(&hist[vs[j]], p);
    }
    if (tid == 0) {
        const int f0 = islot[0][0] | islot[0][1] | islot[0][2] | islot[0][3];
        const int f1 = islot[1][0] | islot[1][1] | islot[1][2] | islot[1][3];
        c_part[bid] = f0 + f1;
    }
    __syncthreads();

    *(float4*)&part_hist[(size_t)bid * NBIN + tid * 4] = *(float4*)&hist[tid * 4];
}

// ---------------- K2: 64 blocks = (b, 128-bin chunk). Hist reduce + chunk GEMM. ----------------
__global__ __launch_bounds__(256) void kvmn_hgemm(
    const float* __restrict__ part_hist,  // [NB1, NBIN]
    const float* __restrict__ value_emb,  // [FVOCAB, E]
    float* __restrict__ partial_out)      // [B, NCH, EE]
{
    __shared__ float Hsh[2][128];
    __shared__ float gs[2][EE];

    const int bid = blockIdx.x;           // 64
    const int b   = bid >> 3;
    const int ch  = bid & 7;              // bins [ch*128, ch*128+128)
    const int tid = threadIdx.x;
    const int bin = tid & 127;
    const int rh  = tid >> 7;             // row half: 0/1

    // reduce 128 hist rows for this b over the 128-bin slice (coalesced 512B slices)
    float s = 0.0f;
    const float* base = part_hist + ((size_t)(b * BPB) + rh * 64) * NBIN + ch * 128 + bin;
    #pragma unroll 8
    for (int r = 0; r < 64; ++r)
        s += base[(size_t)r * NBIN];
    Hsh[rh][bin] = s;
    __syncthreads();
    if (tid < 128) Hsh[0][tid] += Hsh[1][tid];
    __syncthreads();

    // chunk GEMM: pout[e] = sum_{i in [0,128)} H[i] * V[ch*128+i, e]
    const int e  = tid & 127;
    const int hf = tid >> 7;              // bin half: 0/1
    float acc = 0.0f;
    #pragma unroll 8
    for (int i = 0; i < 64; ++i) {
        const int gb = ch * 128 + hf * 64 + i;
        if (gb < 1000)
            acc += Hsh[0][hf * 64 + i] * value_emb[(size_t)gb * EE + e];
    }
    gs[hf][e] = acc;
    __syncthreads();
    if (tid < EE)
        partial_out[((size_t)b * NCH + ch) * EE + tid] = gs[0][tid] + gs[1][tid];
}

// ---------------- K3: 8 blocks: reduce chunks + valid-h divide. ----------------
__global__ __launch_bounds__(256) void kvmn_final(
    const float* __restrict__ partial_out, // [B, NCH, EE]
    const int*   __restrict__ c_part,      // [NB1]
    float* __restrict__ out)               // [B, E]
{
    __shared__ float gs[2][EE];
    __shared__ int   sh_c[128];
    __shared__ float sh_cf;

    const int b   = blockIdx.x;
    const int tid = threadIdx.x;
    const int e   = tid & 127;
    const int hf  = tid >> 7;

    float acc = 0.0f;
    #pragma unroll
    for (int q = 0; q < 4; ++q)
        acc += partial_out[((size_t)b * NCH + hf * 4 + q) * EE + e];
    gs[hf][e] = acc;
    if (tid < BPB) sh_c[tid] = c_part[b * BPB + tid];
    __syncthreads();
    if (tid == 0) {
        int c = 0;
        #pragma unroll 8
        for (int i = 0; i < BPB; ++i) c += sh_c[i];
        sh_cf = (float)c;
    }
    __syncthreads();
    if (tid < EE)
        out[b * EE + tid] = (gs[0][tid] + gs[1][tid]) / sh_cf;
}

extern "C" void kernel_launch(void* const* d_in, const int* in_sizes, int n_in,
                              void* d_out, int out_size, void* d_ws, size_t ws_size,
                              hipStream_t stream) {
    const float* hidden    = (const float*)d_in[0];
    const float* key_emb   = (const float*)d_in[1];
    const float* value_emb = (const float*)d_in[2];
    const int*   key_seq   = (const int*)d_in[3];
    const int*   value_seq = (const int*)d_in[4];
    const int*   mask      = (const int*)d_in[5];

    char* ws = (char*)d_ws;
    float* part_hist   = (float*)ws;                               // 4 MB
    float* partial_out = (float*)(ws + (4u << 20));                // 32 KB
    int*   c_part      = (int*)  (ws + (4u << 20) + (64u << 10));  // 4 KB

    kvmn_attn <<<NB1, 256, 0, stream>>>(hidden, key_emb, key_seq,
                                        value_seq, mask, part_hist, c_part);
    kvmn_hgemm<<<64, 256, 0, stream>>>(part_hist, value_emb, partial_out);
    kvmn_final<<<BB, 256, 0, stream>>>(partial_out, c_part, (float*)d_out);
    (void)in_sizes; (void)n_in; (void)out_size; (void)ws_size;
}